// Round 1
// baseline (32685.184 us; speedup 1.0000x reference)
//
#include <hip/hip_runtime.h>
#include <hip/hip_cooperative_groups.h>

namespace cg = cooperative_groups;

#define B_   128
#define T_   1024
#define DIN  256
#define H_   512
#define DOUT 128
#define NWG  128   // one WG per 4 h-columns
#define HS   4

typedef __attribute__((ext_vector_type(4))) float f32x4;
typedef __attribute__((ext_vector_type(8))) short bf16x8;

__device__ __forceinline__ short f2bf(float f) {
  union { float f; unsigned u; } v; v.f = f;
  unsigned r = v.u + 0x7FFFu + ((v.u >> 16) & 1u);
  return (short)(r >> 16);
}
__device__ __forceinline__ float sigf(float x) { return 1.f / (1.f + __expf(-x)); }

__global__ __launch_bounds__(256, 1) void lstm_coop_kernel(
    const float* __restrict__ x,
    const float* __restrict__ wih0, const float* __restrict__ whh0,
    const float* __restrict__ bih0, const float* __restrict__ bhh0,
    const float* __restrict__ wih1, const float* __restrict__ whh1,
    const float* __restrict__ bih1, const float* __restrict__ bhh1,
    const float* __restrict__ fcw,  const float* __restrict__ fcb,
    void* __restrict__ ws, float* __restrict__ out)
{
  // LDS weight slices: row index lr = 4*jj + gate  (jj in [0,4), gate in {i,f,g,o})
  // padded +8 shorts per row -> 16B-aligned rows, spreads LDS banks
  __shared__ short sWih0[16][264];
  __shared__ short sWhh0[16][520];
  __shared__ short sWih1[16][520];
  __shared__ short sWhh1[16][520];

  const int tid = threadIdx.x;
  const int wg  = blockIdx.x;
  const int j0  = wg * HS;

  short* h0buf = (short*)ws;                    // [2][B_][H_] bf16
  short* h1buf = h0buf + 2 * B_ * H_;           // [2][B_][H_] bf16
  float* h1fin = (float*)(h1buf + 2 * B_ * H_); // [B_][H_] f32

  // ---- load weight slices -> LDS (fp32 -> bf16 RNE) ----
  for (int idx = tid; idx < 16 * DIN; idx += 256) {
    int lr = idx >> 8, k = idx & 255;
    int grow = (lr & 3) * H_ + j0 + (lr >> 2);
    sWih0[lr][k] = f2bf(wih0[(size_t)grow * DIN + k]);
  }
  for (int idx = tid; idx < 16 * H_; idx += 256) {
    int lr = idx >> 9, k = idx & 511;
    int grow = (lr & 3) * H_ + j0 + (lr >> 2);
    sWhh0[lr][k] = f2bf(whh0[(size_t)grow * H_ + k]);
    sWih1[lr][k] = f2bf(wih1[(size_t)grow * H_ + k]);
    sWhh1[lr][k] = f2bf(whh1[(size_t)grow * H_ + k]);
  }

  // ---- zero h0buf[0] and both h1 buffers (read before first write) ----
  {
    int gtid = wg * 256 + tid;                 // 32768 threads
    unsigned* z0 = (unsigned*)h0buf;           // h0buf[0]: 32768 dwords
    z0[gtid] = 0u;
    unsigned* z1 = (unsigned*)h1buf;           // h1buf[0..1]: 65536 dwords
    z1[gtid] = 0u;
    z1[gtid + 32768] = 0u;
  }
  __syncthreads();
  cg::this_grid().sync();

  const int lane = tid & 63;
  const int wid  = tid >> 6;
  const int ln   = lane & 15;   // batch within tile (both operand N-row and C col)
  const int q    = lane >> 4;   // k-subblock for frags AND jj for C rows

  float bias0[4], bias1[4];
#pragma unroll
  for (int g = 0; g < 4; ++g) {
    int rr = g * H_ + j0 + q;
    bias0[g] = bih0[rr] + bhh0[rr];
    bias1[g] = bih1[rr] + bhh1[rr];
  }

  const int bA = (2 * wid) * 16 + ln;      // batch row, tile A
  const int bB = (2 * wid + 1) * 16 + ln;  // batch row, tile B

  float c0[2] = {0.f, 0.f};
  float c1[2] = {0.f, 0.f};

  auto cell0 = [&](int b, float& c, int t, const short* h0rd, short* h0wr) {
    f32x4 acc;
    acc[0] = bias0[0]; acc[1] = bias0[1]; acc[2] = bias0[2]; acc[3] = bias0[3];
    // x part: K = 256
    const float* xrow = x + ((size_t)b * T_ + t) * DIN + q * 8;
#pragma unroll
    for (int ks = 0; ks < 8; ++ks) {
      f32x4 xa = *(const f32x4*)(xrow + ks * 32);
      f32x4 xb = *(const f32x4*)(xrow + ks * 32 + 4);
      bf16x8 bf;
#pragma unroll
      for (int j = 0; j < 4; ++j) { bf[j] = f2bf(xa[j]); bf[4 + j] = f2bf(xb[j]); }
      bf16x8 af = *(const bf16x8*)(&sWih0[ln][ks * 32 + q * 8]);
      acc = __builtin_amdgcn_mfma_f32_16x16x32_bf16(af, bf, acc, 0, 0, 0);
    }
    // h part: K = 512
    const short* hrow = h0rd + (size_t)b * H_ + q * 8;
#pragma unroll
    for (int ks = 0; ks < 16; ++ks) {
      bf16x8 bf = *(const bf16x8*)(hrow + ks * 32);
      bf16x8 af = *(const bf16x8*)(&sWhh0[ln][ks * 32 + q * 8]);
      acc = __builtin_amdgcn_mfma_f32_16x16x32_bf16(af, bf, acc, 0, 0, 0);
    }
    float ig = sigf(acc[0]), fg = sigf(acc[1]), gg = tanhf(acc[2]), og = sigf(acc[3]);
    float cn = fg * c + ig * gg;
    c = cn;
    float hn = og * tanhf(cn);
    h0wr[(size_t)b * H_ + j0 + q] = f2bf(hn);
  };

  auto cell1 = [&](int b, float& c, const short* h0rd, const short* h1rd,
                   short* h1wr, bool last) {
    f32x4 acc;
    acc[0] = bias1[0]; acc[1] = bias1[1]; acc[2] = bias1[2]; acc[3] = bias1[3];
    const short* h0p = h0rd + (size_t)b * H_ + q * 8;
#pragma unroll
    for (int ks = 0; ks < 16; ++ks) {
      bf16x8 bf = *(const bf16x8*)(h0p + ks * 32);
      bf16x8 af = *(const bf16x8*)(&sWih1[ln][ks * 32 + q * 8]);
      acc = __builtin_amdgcn_mfma_f32_16x16x32_bf16(af, bf, acc, 0, 0, 0);
    }
    const short* h1p = h1rd + (size_t)b * H_ + q * 8;
#pragma unroll
    for (int ks = 0; ks < 16; ++ks) {
      bf16x8 bf = *(const bf16x8*)(h1p + ks * 32);
      bf16x8 af = *(const bf16x8*)(&sWhh1[ln][ks * 32 + q * 8]);
      acc = __builtin_amdgcn_mfma_f32_16x16x32_bf16(af, bf, acc, 0, 0, 0);
    }
    float ig = sigf(acc[0]), fg = sigf(acc[1]), gg = tanhf(acc[2]), og = sigf(acc[3]);
    float cn = fg * c + ig * gg;
    c = cn;
    float hn = og * tanhf(cn);
    h1wr[(size_t)b * H_ + j0 + q] = f2bf(hn);
    if (last) h1fin[(size_t)b * H_ + j0 + q] = hn;
  };

  // ---- main recurrence: round r does layer0 step r and layer1 step r-1 ----
  for (int r = 0; r <= T_; ++r) {
    short* h0rd = h0buf + (r & 1) * (B_ * H_);
    short* h0wr = h0buf + ((r + 1) & 1) * (B_ * H_);
    short* h1rd = h1buf + (r & 1) * (B_ * H_);
    short* h1wr = h1buf + ((r + 1) & 1) * (B_ * H_);
    if (r < T_) {
      cell0(bA, c0[0], r, h0rd, h0wr);
      cell0(bB, c0[1], r, h0rd, h0wr);
    }
    if (r >= 1) {
      bool last = (r == T_);
      cell1(bA, c1[0], h0rd, h1rd, h1wr, last);
      cell1(bB, c1[1], h0rd, h1rd, h1wr, last);
    }
    cg::this_grid().sync();
  }

  // ---- FC epilogue: WG = batch row, thread = output column ----
  if (tid < DOUT) {
    const float* hrow = h1fin + (size_t)wg * H_;
    const float* wrow = fcw + (size_t)tid * H_;
    float a = fcb[tid];
    for (int j = 0; j < H_; j += 4) {
      f32x4 hv = *(const f32x4*)(hrow + j);
      f32x4 wv = *(const f32x4*)(wrow + j);
      a += hv[0] * wv[0] + hv[1] * wv[1] + hv[2] * wv[2] + hv[3] * wv[3];
    }
    out[(size_t)wg * DOUT + tid] = a;
  }
}

extern "C" void kernel_launch(void* const* d_in, const int* in_sizes, int n_in,
                              void* d_out, int out_size, void* d_ws, size_t ws_size,
                              hipStream_t stream) {
  const float* x    = (const float*)d_in[0];
  const float* wih0 = (const float*)d_in[1];
  const float* whh0 = (const float*)d_in[2];
  const float* bih0 = (const float*)d_in[3];
  const float* bhh0 = (const float*)d_in[4];
  const float* wih1 = (const float*)d_in[5];
  const float* whh1 = (const float*)d_in[6];
  const float* bih1 = (const float*)d_in[7];
  const float* bhh1 = (const float*)d_in[8];
  const float* fcw  = (const float*)d_in[9];
  const float* fcb  = (const float*)d_in[10];
  float* out = (float*)d_out;

  void* args[] = { (void*)&x, (void*)&wih0, (void*)&whh0, (void*)&bih0, (void*)&bhh0,
                   (void*)&wih1, (void*)&whh1, (void*)&bih1, (void*)&bhh1,
                   (void*)&fcw, (void*)&fcb, (void*)&d_ws, (void*)&out };
  hipLaunchCooperativeKernel((const void*)lstm_coop_kernel,
                             dim3(NWG), dim3(256), args, 0, stream);
}

// Round 2
// 15990.329 us; speedup vs baseline: 2.0441x; 2.0441x over previous
//
#include <hip/hip_runtime.h>

#define B_   128
#define T_   1024
#define DIN  256
#define H_   512
#define DOUT 128
#define NWG  256   // 128 column-groups x 2 batch-halves

typedef __attribute__((ext_vector_type(4))) float f32x4;
typedef __attribute__((ext_vector_type(8))) short bf16x8;

__device__ __forceinline__ short f2bf(float f) {
  union { float f; unsigned u; } v; v.f = f;
  unsigned r = v.u + 0x7FFFu + ((v.u >> 16) & 1u);
  return (short)(r >> 16);
}
__device__ __forceinline__ float sigf(float x) { return 1.f / (1.f + __expf(-x)); }

// ---- agent-scope coherent access (bypasses non-coherent per-XCD L2) ----
__device__ __forceinline__ void st_bf(short* p, short v) {
  __hip_atomic_store((unsigned short*)p, (unsigned short)v,
                     __ATOMIC_RELAXED, __HIP_MEMORY_SCOPE_AGENT);
}
__device__ __forceinline__ void st_f32(float* p, float v) {
  __hip_atomic_store(p, v, __ATOMIC_RELAXED, __HIP_MEMORY_SCOPE_AGENT);
}
__device__ __forceinline__ bf16x8 ldfrag(const short* p) {
  union { bf16x8 v; unsigned long long q[2]; } u;
  u.q[0] = __hip_atomic_load((const unsigned long long*)p,
                             __ATOMIC_RELAXED, __HIP_MEMORY_SCOPE_AGENT);
  u.q[1] = __hip_atomic_load((const unsigned long long*)(p + 4),
                             __ATOMIC_RELAXED, __HIP_MEMORY_SCOPE_AGENT);
  return u.v;
}

// ws layout: h0buf [2][B][H] bf16 (256KB) | h1buf [2][B][H] bf16 (256KB)
//            h1fin [B][H] f32 (256KB)    | bar (4B)
#define WS_H1OFF   (2 * B_ * H_)
#define WS_FINOFF  (4 * B_ * H_)          // in shorts
#define WS_ZERO_DW (131072)               // 512KB of h bufs, in dwords

__global__ void lstm_init_kernel(void* ws) {
  int gid = blockIdx.x * blockDim.x + threadIdx.x;
  unsigned* p = (unsigned*)ws;
  if (gid < WS_ZERO_DW)
    __hip_atomic_store(p + gid, 0u, __ATOMIC_RELAXED, __HIP_MEMORY_SCOPE_AGENT);
  if (gid == 0) {
    unsigned* bar = (unsigned*)((short*)ws + WS_FINOFF + 2 * B_ * H_); // after h1fin
    __hip_atomic_store(bar, 0u, __ATOMIC_RELAXED, __HIP_MEMORY_SCOPE_AGENT);
  }
}

__global__ __launch_bounds__(256, 1) void lstm_coop_kernel(
    const float* __restrict__ x,
    const float* __restrict__ wih0, const float* __restrict__ whh0,
    const float* __restrict__ bih0, const float* __restrict__ bhh0,
    const float* __restrict__ wih1, const float* __restrict__ whh1,
    const float* __restrict__ bih1, const float* __restrict__ bhh1,
    const float* __restrict__ fcw,  const float* __restrict__ fcb,
    void* __restrict__ ws, float* __restrict__ out)
{
  __shared__ short sWih0[16][264];
  __shared__ short sWhh0[16][520];
  __shared__ short sWih1[16][520];
  __shared__ short sWhh1[16][520];

  const int tid  = threadIdx.x;
  const int wg   = blockIdx.x;
  const int cgid = wg >> 1;        // column group (4 h-cols)
  const int bh   = wg & 1;         // batch half (64 batches)
  const int j0   = cgid * 4;

  short* h0buf = (short*)ws;
  short* h1buf = h0buf + WS_H1OFF;
  float* h1fin = (float*)(h0buf + WS_FINOFF);
  unsigned* bar = (unsigned*)(h1fin + B_ * H_);

  // ---- weight slices -> LDS (fp32 -> bf16 RNE); row lr = 4*jj + gate ----
  for (int idx = tid; idx < 16 * DIN; idx += 256) {
    int lr = idx >> 8, k = idx & 255;
    int grow = (lr & 3) * H_ + j0 + (lr >> 2);
    sWih0[lr][k] = f2bf(wih0[(size_t)grow * DIN + k]);
  }
  for (int idx = tid; idx < 16 * H_; idx += 256) {
    int lr = idx >> 9, k = idx & 511;
    int grow = (lr & 3) * H_ + j0 + (lr >> 2);
    sWhh0[lr][k] = f2bf(whh0[(size_t)grow * H_ + k]);
    sWih1[lr][k] = f2bf(wih1[(size_t)grow * H_ + k]);
    sWhh1[lr][k] = f2bf(whh1[(size_t)grow * H_ + k]);
  }
  __syncthreads();

  const int lane = tid & 63;
  const int wid  = tid >> 6;
  const int ln   = lane & 15;      // batch within tile / C col
  const int q    = lane >> 4;      // k-subblock / C row-group (jj)
  const int b    = bh * 64 + wid * 16 + ln;   // this lane's batch row

  float bias0[4], bias1[4];
#pragma unroll
  for (int g = 0; g < 4; ++g) {
    int rr = g * H_ + j0 + q;
    bias0[g] = bih0[rr] + bhh0[rr];
    bias1[g] = bih1[rr] + bhh1[rr];
  }

  // x prefetch registers (bf16, one step)
  bf16x8 xp[8];
  auto xpref = [&](int t) {
    const float* xrow = x + ((size_t)b * T_ + t) * DIN + q * 8;
#pragma unroll
    for (int ks = 0; ks < 8; ++ks) {
      f32x4 xa = *(const f32x4*)(xrow + ks * 32);
      f32x4 xb = *(const f32x4*)(xrow + ks * 32 + 4);
#pragma unroll
      for (int j = 0; j < 4; ++j) { xp[ks][j] = f2bf(xa[j]); xp[ks][4 + j] = f2bf(xb[j]); }
    }
  };
  xpref(0);

  float c0v = 0.f, c1v = 0.f;

  for (int r = 0; r <= T_; ++r) {
    short* h0rd = h0buf + (r & 1) * (B_ * H_);
    short* h0wr = h0buf + ((r + 1) & 1) * (B_ * H_);
    short* h1rd = h1buf + (r & 1) * (B_ * H_);
    short* h1wr = h1buf + ((r + 1) & 1) * (B_ * H_);

    if (r < T_) {  // layer 0, step r
      f32x4 accA, accB;
      accA[0] = bias0[0]; accA[1] = bias0[1]; accA[2] = bias0[2]; accA[3] = bias0[3];
      accB[0] = 0.f; accB[1] = 0.f; accB[2] = 0.f; accB[3] = 0.f;
#pragma unroll
      for (int ks = 0; ks < 8; ++ks) {
        bf16x8 af = *(const bf16x8*)(&sWih0[ln][ks * 32 + q * 8]);
        if (ks & 1) accB = __builtin_amdgcn_mfma_f32_16x16x32_bf16(af, xp[ks], accB, 0, 0, 0);
        else        accA = __builtin_amdgcn_mfma_f32_16x16x32_bf16(af, xp[ks], accA, 0, 0, 0);
      }
      const short* hrow = h0rd + (size_t)b * H_ + q * 8;
#pragma unroll
      for (int ks = 0; ks < 16; ++ks) {
        bf16x8 bf = ldfrag(hrow + ks * 32);
        bf16x8 af = *(const bf16x8*)(&sWhh0[ln][ks * 32 + q * 8]);
        if (ks & 1) accB = __builtin_amdgcn_mfma_f32_16x16x32_bf16(af, bf, accB, 0, 0, 0);
        else        accA = __builtin_amdgcn_mfma_f32_16x16x32_bf16(af, bf, accA, 0, 0, 0);
      }
      f32x4 acc = accA + accB;
      float ig = sigf(acc[0]), fg = sigf(acc[1]), gg = tanhf(acc[2]), og = sigf(acc[3]);
      float cn = fg * c0v + ig * gg;
      c0v = cn;
      st_bf(h0wr + (size_t)b * H_ + j0 + q, f2bf(og * tanhf(cn)));
    }

    if (r >= 1) {  // layer 1, step r-1
      f32x4 accA, accB;
      accA[0] = bias1[0]; accA[1] = bias1[1]; accA[2] = bias1[2]; accA[3] = bias1[3];
      accB[0] = 0.f; accB[1] = 0.f; accB[2] = 0.f; accB[3] = 0.f;
      const short* h0p = h0rd + (size_t)b * H_ + q * 8;
      const short* h1p = h1rd + (size_t)b * H_ + q * 8;
#pragma unroll
      for (int ks = 0; ks < 16; ++ks) {
        bf16x8 bf = ldfrag(h0p + ks * 32);
        bf16x8 af = *(const bf16x8*)(&sWih1[ln][ks * 32 + q * 8]);
        if (ks & 1) accB = __builtin_amdgcn_mfma_f32_16x16x32_bf16(af, bf, accB, 0, 0, 0);
        else        accA = __builtin_amdgcn_mfma_f32_16x16x32_bf16(af, bf, accA, 0, 0, 0);
      }
#pragma unroll
      for (int ks = 0; ks < 16; ++ks) {
        bf16x8 bf = ldfrag(h1p + ks * 32);
        bf16x8 af = *(const bf16x8*)(&sWhh1[ln][ks * 32 + q * 8]);
        if (ks & 1) accB = __builtin_amdgcn_mfma_f32_16x16x32_bf16(af, bf, accB, 0, 0, 0);
        else        accA = __builtin_amdgcn_mfma_f32_16x16x32_bf16(af, bf, accA, 0, 0, 0);
      }
      f32x4 acc = accA + accB;
      float ig = sigf(acc[0]), fg = sigf(acc[1]), gg = tanhf(acc[2]), og = sigf(acc[3]);
      float cn = fg * c1v + ig * gg;
      c1v = cn;
      float hn = og * tanhf(cn);
      st_bf(h1wr + (size_t)b * H_ + j0 + q, f2bf(hn));
      if (r == T_) st_f32(h1fin + (size_t)b * H_ + j0 + q, hn);
    }

    // ---- lightweight device barrier (no cache flush) ----
    asm volatile("s_waitcnt vmcnt(0)" ::: "memory");  // this wave's coherent stores at L3
    __syncthreads();                                   // all waves drained
    if (tid == 0)
      __hip_atomic_fetch_add(bar, 1u, __ATOMIC_RELAXED, __HIP_MEMORY_SCOPE_AGENT);
    if (r + 1 < T_) xpref(r + 1);                      // hide x latency under the wait
    if (tid == 0) {
      const unsigned tgt = (unsigned)(r + 1) * NWG;
      while (__hip_atomic_load(bar, __ATOMIC_RELAXED, __HIP_MEMORY_SCOPE_AGENT) < tgt)
        __builtin_amdgcn_s_sleep(2);
    }
    __syncthreads();
    asm volatile("" ::: "memory");                     // keep h loads below the barrier
  }

  // ---- FC epilogue: WG = batch row, thread = output column ----
  if (wg < B_ && tid < DOUT) {
    const float* hrow = h1fin + (size_t)wg * H_;
    const float* wrow = fcw + (size_t)tid * H_;
    float a = fcb[tid];
    for (int j = 0; j < H_; j += 2) {
      union { unsigned long long q; float f[2]; } c;
      c.q = __hip_atomic_load((const unsigned long long*)(hrow + j),
                              __ATOMIC_RELAXED, __HIP_MEMORY_SCOPE_AGENT);
      a += c.f[0] * wrow[j] + c.f[1] * wrow[j + 1];
    }
    out[(size_t)wg * DOUT + tid] = a;
  }
}

extern "C" void kernel_launch(void* const* d_in, const int* in_sizes, int n_in,
                              void* d_out, int out_size, void* d_ws, size_t ws_size,
                              hipStream_t stream) {
  const float* x    = (const float*)d_in[0];
  const float* wih0 = (const float*)d_in[1];
  const float* whh0 = (const float*)d_in[2];
  const float* bih0 = (const float*)d_in[3];
  const float* bhh0 = (const float*)d_in[4];
  const float* wih1 = (const float*)d_in[5];
  const float* whh1 = (const float*)d_in[6];
  const float* bih1 = (const float*)d_in[7];
  const float* bhh1 = (const float*)d_in[8];
  const float* fcw  = (const float*)d_in[9];
  const float* fcb  = (const float*)d_in[10];
  float* out = (float*)d_out;

  hipLaunchKernelGGL(lstm_init_kernel, dim3(512), dim3(256), 0, stream, d_ws);

  void* args[] = { (void*)&x, (void*)&wih0, (void*)&whh0, (void*)&bih0, (void*)&bhh0,
                   (void*)&wih1, (void*)&whh1, (void*)&bih1, (void*)&bhh1,
                   (void*)&fcw, (void*)&fcb, (void*)&d_ws, (void*)&out };
  hipLaunchCooperativeKernel((const void*)lstm_coop_kernel,
                             dim3(NWG), dim3(256), args, 0, stream);
}

// Round 3
// 7323.792 us; speedup vs baseline: 4.4629x; 2.1833x over previous
//
#include <hip/hip_runtime.h>

#define B_   128
#define T_   1024
#define DIN  256
#define H_   512
#define DOUT 128
#define NWG  256   // 128 column-groups x 2 batch-halves

typedef __attribute__((ext_vector_type(4))) float f32x4;
typedef __attribute__((ext_vector_type(8))) short bf16x8;
typedef __attribute__((ext_vector_type(4))) short bf16x4;

// ---- ws byte layout ----
#define H0_OFF   0u                      // [2][64][128][8] bf16 = 256KB
#define H1_OFF   (256u << 10)            // [2][64][128][8] bf16 = 256KB
#define FIN_OFF  (512u << 10)            // [128][512] f32 = 256KB
#define BAR_OFF  (768u << 10)            // 4B
#define XB_OFF   ((768u << 10) + 256u)   // [1024][32][128][8] bf16 = 64MB
#define XB_BYTES ((size_t)T_ * 32 * 128 * 8 * 2)

__device__ __forceinline__ short f2bf(float f) {
  union { float f; unsigned u; } v; v.f = f;
  unsigned r = v.u + 0x7FFFu + ((v.u >> 16) & 1u);
  return (short)(r >> 16);
}
__device__ __forceinline__ float sigf(float x) { return 1.f / (1.f + __expf(-x)); }

// agent-scope coherent 2B/4B stores (bypass non-coherent per-XCD L2)
__device__ __forceinline__ void st_bf(short* p, short v) {
  __hip_atomic_store((unsigned short*)p, (unsigned short)v,
                     __ATOMIC_RELAXED, __HIP_MEMORY_SCOPE_AGENT);
}
__device__ __forceinline__ void st_f32(float* p, float v) {
  __hip_atomic_store(p, v, __ATOMIC_RELAXED, __HIP_MEMORY_SCOPE_AGENT);
}
// coherent 16B load, no wait (caller drains vmcnt before use)
__device__ __forceinline__ void ld16(bf16x8& d, const short* p) {
  asm volatile("global_load_dwordx4 %0, %1, off sc0 sc1" : "=v"(d) : "v"(p));
}

__global__ void lstm_init_kernel(void* ws) {
  int gid = blockIdx.x * blockDim.x + threadIdx.x;   // 131072 threads
  unsigned* p = (unsigned*)ws;                       // h0+h1 = 512KB = 131072 dw
  __hip_atomic_store(p + gid, 0u, __ATOMIC_RELAXED, __HIP_MEMORY_SCOPE_AGENT);
  if (gid == 0) {
    unsigned* bar = (unsigned*)((char*)ws + BAR_OFF);
    __hip_atomic_store(bar, 0u, __ATOMIC_RELAXED, __HIP_MEMORY_SCOPE_AGENT);
  }
}

// x fp32 [B][T][DIN] -> xb bf16 fragment-major [T][32][128][8]
__global__ void xconv_kernel(const float* __restrict__ x, short* __restrict__ xb) {
  int blk = blockIdx.x;            // t*32 + g
  int t = blk >> 5, g = blk & 31;
  int b = threadIdx.x >> 1, hf = (threadIdx.x & 1) * 4;
  f32x4 v = *(const f32x4*)(x + ((size_t)b * T_ + t) * DIN + g * 8 + hf);
  bf16x4 o;
#pragma unroll
  for (int j = 0; j < 4; ++j) o[j] = f2bf(v[j]);
  *(bf16x4*)(xb + ((size_t)(t * 32 + g) * 128 + b) * 8 + hf) = o;
}

__global__ __launch_bounds__(256, 1) void lstm_coop_kernel(
    const float* __restrict__ x,
    const float* __restrict__ wih0, const float* __restrict__ whh0,
    const float* __restrict__ bih0, const float* __restrict__ bhh0,
    const float* __restrict__ wih1, const float* __restrict__ whh1,
    const float* __restrict__ bih1, const float* __restrict__ bhh1,
    const float* __restrict__ fcw,  const float* __restrict__ fcb,
    const short* __restrict__ xb,
    void* __restrict__ ws, float* __restrict__ out)
{
  __shared__ short sWih0[16][264];
  __shared__ short sWhh0[16][520];
  __shared__ short sWih1[16][520];
  __shared__ short sWhh1[16][520];

  const int tid  = threadIdx.x;
  const int wg   = blockIdx.x;
  const int cgid = wg >> 1;
  const int bh   = wg & 1;
  const int j0   = cgid * 4;

  char* wsb = (char*)ws;
  short* h0buf = (short*)(wsb + H0_OFF);
  short* h1buf = (short*)(wsb + H1_OFF);
  float* h1fin = (float*)(wsb + FIN_OFF);
  unsigned* bar = (unsigned*)(wsb + BAR_OFF);

  // weight slices -> LDS (fp32 -> bf16 RNE); row lr = 4*jj + gate
  for (int idx = tid; idx < 16 * DIN; idx += 256) {
    int lr = idx >> 8, k = idx & 255;
    int grow = (lr & 3) * H_ + j0 + (lr >> 2);
    sWih0[lr][k] = f2bf(wih0[(size_t)grow * DIN + k]);
  }
  for (int idx = tid; idx < 16 * H_; idx += 256) {
    int lr = idx >> 9, k = idx & 511;
    int grow = (lr & 3) * H_ + j0 + (lr >> 2);
    sWhh0[lr][k] = f2bf(whh0[(size_t)grow * H_ + k]);
    sWih1[lr][k] = f2bf(wih1[(size_t)grow * H_ + k]);
    sWhh1[lr][k] = f2bf(whh1[(size_t)grow * H_ + k]);
  }
  __syncthreads();

  const int lane = tid & 63;
  const int wid  = tid >> 6;
  const int ln   = lane & 15;               // batch within tile / C col
  const int q    = lane >> 4;               // k-subblock / C row-group (jj)
  const int b    = bh * 64 + wid * 16 + ln; // this lane's batch row
  const int jj   = j0 + q;                  // this lane's h column
  const int hwof = (jj >> 3) * 1024 + (jj & 7);  // write offset (+ b*8)

  float bias0[4], bias1[4];
#pragma unroll
  for (int g = 0; g < 4; ++g) {
    int rr = g * H_ + j0 + q;
    bias0[g] = bih0[rr] + bhh0[rr];
    bias1[g] = bih1[rr] + bhh1[rr];
  }

  // x prefetch (one step ahead, plain cached loads)
  bf16x8 xp[8];
  auto xpref = [&](int t) {
    if (xb) {
      const short* p = xb + ((size_t)(t * 32 + q) * 128 + b) * 8;
#pragma unroll
      for (int ks = 0; ks < 8; ++ks) xp[ks] = *(const bf16x8*)(p + ks * 4096);
    } else {
      const float* xrow = x + ((size_t)b * T_ + t) * DIN + q * 8;
#pragma unroll
      for (int ks = 0; ks < 8; ++ks) {
        f32x4 xa = *(const f32x4*)(xrow + ks * 32);
        f32x4 xc = *(const f32x4*)(xrow + ks * 32 + 4);
#pragma unroll
        for (int j = 0; j < 4; ++j) { xp[ks][j] = f2bf(xa[j]); xp[ks][4 + j] = f2bf(xc[j]); }
      }
    }
  };
  xpref(0);

  float c0v = 0.f, c1v = 0.f;

  for (int r = 0; r <= T_; ++r) {
    const short* h0rd = h0buf + (r & 1) * 65536;
    short*       h0wr = h0buf + ((r + 1) & 1) * 65536;
    const short* h1rd = h1buf + (r & 1) * 65536;
    short*       h1wr = h1buf + ((r + 1) & 1) * 65536;

    // ---- coherent fragment loads: h0 (shared by L0-whh0 and L1-wih1) + h1 ----
    bf16x8 f0[16], f1[16];
    {
      const short* p0 = h0rd + q * 1024 + (size_t)b * 8;
      const short* p1 = h1rd + q * 1024 + (size_t)b * 8;
#pragma unroll
      for (int ks = 0; ks < 16; ++ks) ld16(f0[ks], p0 + ks * 4096);
#pragma unroll
      for (int ks = 0; ks < 16; ++ks) ld16(f1[ks], p1 + ks * 4096);
      asm volatile("s_waitcnt vmcnt(0)" ::: "memory");
      __builtin_amdgcn_sched_barrier(0);
    }

    if (r < T_) {  // layer 0, step r
      f32x4 accA, accB;
      accA[0] = bias0[0]; accA[1] = bias0[1]; accA[2] = bias0[2]; accA[3] = bias0[3];
      accB[0] = 0.f; accB[1] = 0.f; accB[2] = 0.f; accB[3] = 0.f;
#pragma unroll
      for (int ks = 0; ks < 8; ++ks) {
        bf16x8 af = *(const bf16x8*)(&sWih0[ln][ks * 32 + q * 8]);
        if (ks & 1) accB = __builtin_amdgcn_mfma_f32_16x16x32_bf16(af, xp[ks], accB, 0, 0, 0);
        else        accA = __builtin_amdgcn_mfma_f32_16x16x32_bf16(af, xp[ks], accA, 0, 0, 0);
      }
#pragma unroll
      for (int ks = 0; ks < 16; ++ks) {
        bf16x8 af = *(const bf16x8*)(&sWhh0[ln][ks * 32 + q * 8]);
        if (ks & 1) accB = __builtin_amdgcn_mfma_f32_16x16x32_bf16(af, f0[ks], accB, 0, 0, 0);
        else        accA = __builtin_amdgcn_mfma_f32_16x16x32_bf16(af, f0[ks], accA, 0, 0, 0);
      }
      f32x4 acc = accA + accB;
      float ig = sigf(acc[0]), fg = sigf(acc[1]), gg = tanhf(acc[2]), og = sigf(acc[3]);
      float cn = fg * c0v + ig * gg;
      c0v = cn;
      st_bf(h0wr + hwof + (size_t)b * 8, f2bf(og * tanhf(cn)));
    }

    if (r >= 1) {  // layer 1, step r-1
      f32x4 accA, accB;
      accA[0] = bias1[0]; accA[1] = bias1[1]; accA[2] = bias1[2]; accA[3] = bias1[3];
      accB[0] = 0.f; accB[1] = 0.f; accB[2] = 0.f; accB[3] = 0.f;
#pragma unroll
      for (int ks = 0; ks < 16; ++ks) {
        bf16x8 af = *(const bf16x8*)(&sWih1[ln][ks * 32 + q * 8]);
        if (ks & 1) accB = __builtin_amdgcn_mfma_f32_16x16x32_bf16(af, f0[ks], accB, 0, 0, 0);
        else        accA = __builtin_amdgcn_mfma_f32_16x16x32_bf16(af, f0[ks], accA, 0, 0, 0);
      }
#pragma unroll
      for (int ks = 0; ks < 16; ++ks) {
        bf16x8 af = *(const bf16x8*)(&sWhh1[ln][ks * 32 + q * 8]);
        if (ks & 1) accB = __builtin_amdgcn_mfma_f32_16x16x32_bf16(af, f1[ks], accB, 0, 0, 0);
        else        accA = __builtin_amdgcn_mfma_f32_16x16x32_bf16(af, f1[ks], accA, 0, 0, 0);
      }
      f32x4 acc = accA + accB;
      float ig = sigf(acc[0]), fg = sigf(acc[1]), gg = tanhf(acc[2]), og = sigf(acc[3]);
      float cn = fg * c1v + ig * gg;
      c1v = cn;
      float hn = og * tanhf(cn);
      st_bf(h1wr + hwof + (size_t)b * 8, f2bf(hn));
      if (r == T_) st_f32(h1fin + (size_t)b * H_ + jj, hn);
    }

    // ---- lightweight device barrier (no cache flush) ----
    asm volatile("s_waitcnt vmcnt(0)" ::: "memory");
    __syncthreads();
    if (tid == 0)
      __hip_atomic_fetch_add(bar, 1u, __ATOMIC_RELAXED, __HIP_MEMORY_SCOPE_AGENT);
    if (r + 1 < T_) xpref(r + 1);   // hide x fetch under the wait
    if (tid == 0) {
      const unsigned tgt = (unsigned)(r + 1) * NWG;
      while (__hip_atomic_load(bar, __ATOMIC_RELAXED, __HIP_MEMORY_SCOPE_AGENT) < tgt)
        __builtin_amdgcn_s_sleep(1);
    }
    __syncthreads();
    asm volatile("" ::: "memory");
  }

  // ---- FC epilogue: WG = batch row, thread = output column ----
  if (wg < B_ && tid < DOUT) {
    const float* hrow = h1fin + (size_t)wg * H_;
    const float* wrow = fcw + (size_t)tid * H_;
    float a = fcb[tid];
    for (int j = 0; j < H_; j += 2) {
      union { unsigned long long q; float f[2]; } c;
      c.q = __hip_atomic_load((const unsigned long long*)(hrow + j),
                              __ATOMIC_RELAXED, __HIP_MEMORY_SCOPE_AGENT);
      a += c.f[0] * wrow[j] + c.f[1] * wrow[j + 1];
    }
    out[(size_t)wg * DOUT + tid] = a;
  }
}

extern "C" void kernel_launch(void* const* d_in, const int* in_sizes, int n_in,
                              void* d_out, int out_size, void* d_ws, size_t ws_size,
                              hipStream_t stream) {
  const float* x    = (const float*)d_in[0];
  const float* wih0 = (const float*)d_in[1];
  const float* whh0 = (const float*)d_in[2];
  const float* bih0 = (const float*)d_in[3];
  const float* bhh0 = (const float*)d_in[4];
  const float* wih1 = (const float*)d_in[5];
  const float* whh1 = (const float*)d_in[6];
  const float* bih1 = (const float*)d_in[7];
  const float* bhh1 = (const float*)d_in[8];
  const float* fcw  = (const float*)d_in[9];
  const float* fcb  = (const float*)d_in[10];
  float* out = (float*)d_out;

  char* wsb = (char*)d_ws;
  bool use_xb = ws_size >= (size_t)XB_OFF + XB_BYTES;
  short* xbw = use_xb ? (short*)(wsb + XB_OFF) : nullptr;
  const short* xb = xbw;

  hipLaunchKernelGGL(lstm_init_kernel, dim3(512), dim3(256), 0, stream, d_ws);
  if (use_xb)
    hipLaunchKernelGGL(xconv_kernel, dim3(T_ * 32), dim3(256), 0, stream, x, xbw);

  void* args[] = { (void*)&x, (void*)&wih0, (void*)&whh0, (void*)&bih0, (void*)&bhh0,
                   (void*)&wih1, (void*)&whh1, (void*)&bih1, (void*)&bhh1,
                   (void*)&fcw, (void*)&fcb, (void*)&xb, (void*)&d_ws, (void*)&out };
  hipLaunchCooperativeKernel((const void*)lstm_coop_kernel,
                             dim3(NWG), dim3(256), args, 0, stream);
}